// Round 15
// baseline (678.619 us; speedup 1.0000x reference)
//
#include <hip/hip_runtime.h>

// BiCLSTM: S=16,B=4,Cin=32,Co=32,H=W=128. fp32 in/out.
// FP16 MFMA implicit-GEMM, OPERAND-SWAP round: mfma(A=weights, B=pixels) so D's
// col=lane&15 is the PIXEL -> epilogue c/out/h accesses are lane-contiguous
// (was: q-plane scatter, ~64 lines per wave-op). Loads/layouts unchanged from r14.
#define S_ 16
#define B_ 4
#define H_ 128
#define W_ 128
#define HW_ (H_ * W_)
#define AH 18
#define AW 34
#define NPOS (AH * AW)          // 612
#define TILE_ELEMS (NPOS * 32)  // 19584 halves per tile A-block

typedef __attribute__((ext_vector_type(8))) _Float16 half8;
typedef __attribute__((ext_vector_type(4))) _Float16 half4;
typedef __attribute__((ext_vector_type(4))) float f32x4;

__device__ __forceinline__ float sigf(float x) { return 1.f / (1.f + __expf(-x)); }
__device__ __forceinline__ float tanhf_(float x) { return 2.f / (1.f + __expf(-2.f * x)) - 1.f; }

__device__ __forceinline__ void gl2lds16(const _Float16* g, _Float16* l) {
    __builtin_amdgcn_global_load_lds(
        (const __attribute__((address_space(1))) unsigned int*)g,
        (__attribute__((address_space(3))) unsigned int*)l, 16, 0, 0);
}

// ---- W-fragment packing: [dir][ks=18][nf=8][lane=64][e=8] fp16 (unchanged bytes) ----
__global__ void prep_pack(const float* __restrict__ Wf, const float* __restrict__ Wb,
                          _Float16* __restrict__ wpk) {
    int id = blockIdx.x * 256 + threadIdx.x;  // 18432
    if (id >= 18432) return;
    int l = id & 63;
    int nf = (id >> 6) & 7;
    int ks = (id >> 9) % 18;
    int d = id / 9216;
    const float* Wsrc = d ? Wb : Wf;
    int tap = ks >> 1, half = ks & 1;
    int dy = tap / 3, dx = tap - dy * 3;
    int co = nf * 16 + (l & 15);
    _Float16* dst = wpk + (size_t)d * 73728 + ((size_t)(ks * 8 + nf) * 64 + l) * 8;
#pragma unroll
    for (int e = 0; e < 8; ++e) {
        int ci = half * 32 + (l >> 4) * 8 + e;
        dst[e] = (_Float16)Wsrc[((co * 64 + ci) * 3 + dy) * 3 + dx];
    }
}

// ---- One-time x -> 16x32-tile layout [ts][b][tile32][pos612][ci32] fp16 ----
__global__ void prep_xtiles(const float* __restrict__ x, _Float16* __restrict__ xt) {
    int id = blockIdx.x * 256 + threadIdx.x;  // 5,013,504
    if (id >= 16 * 4 * 32 * NPOS * 4) return;
    int cb = id & 3;
    int u = id >> 2;            // [ts][b][tile][pos]
    int pos = u % NPOS;
    int v = u / NPOS;
    int tile = v & 31;
    v >>= 5;
    int b = v & 3;
    int ts = v >> 2;
    int ar = pos / AW, ac = pos - ar * AW;
    int gy = (tile >> 2) * 16 + ar - 1;
    int gx = (tile & 3) * 32 + ac - 1;
    bool inb = ((unsigned)gy < 128u) && ((unsigned)gx < 128u);
    const float* g = x + ((size_t)(ts * 4 + b) * 32 + cb * 8) * HW_ + (size_t)gy * W_ + gx;
    half8 vv;
#pragma unroll
    for (int e = 0; e < 8; ++e)
        vv[e] = inb ? (_Float16)__builtin_nontemporal_load(g + e * HW_) : (_Float16)0.f;
    *(half8*)(xt + (size_t)u * 32 + cb * 8) = vv;
}

// Pixel-frag loaders (now the MFMA *B* operand; same bytes as before).
__device__ __forceinline__ half8 lda(const _Float16* __restrict__ base, int f, int dy,
                                     int dx, int px, int kg, int wq) {
    int pos = (wq * 2 + (f >> 1) + dy) * AW + (f & 1) * 16 + px + dx;
    return *(const half8*)(base + (size_t)pos * 32 + kg * 8);
}
__device__ __forceinline__ half8 lda_nt(const _Float16* __restrict__ base, int f, int dy,
                                        int dx, int px, int kg, int wq) {
    int pos = (wq * 2 + (f >> 1) + dy) * AW + (f & 1) * 16 + px + dx;
    return __builtin_nontemporal_load((const half8*)(base + (size_t)pos * 32 + kg * 8));
}

extern __shared__ _Float16 bsh[];  // 147,456 B: [ks*8+nf][lane][e=8], one dir

// One timestep, both directions. grid (8, 32): x = dirb, y = tile. 512 thr.
__global__ __launch_bounds__(512, 1)
void convlstm_step(const _Float16* __restrict__ xtiles,
                   const _Float16* __restrict__ hin,
                   _Float16* __restrict__ hout,
                   const _Float16* __restrict__ wpk,
                   const float* __restrict__ biasf, const float* __restrict__ biasb,
                   _Float16* __restrict__ cst,          // fp16 c-state [dirb][32][HW]
                   float* __restrict__ out, int t) {
    const int dirb = blockIdx.x;
    const int tile = blockIdx.y;
    const int dir = dirb >> 2, b = dirb & 3;
    const int ts = dir ? (S_ - 1 - t) : t;

    const _Float16* base_x = xtiles + ((size_t)(ts * 4 + b) * 32 + tile) * TILE_ELEMS;
    const _Float16* base_h = hin + ((size_t)dirb * 32 + tile) * TILE_ELEMS;
    _Float16* hob = hout + (size_t)dirb * 32 * TILE_ELEMS;
    const _Float16* bw = wpk + (size_t)dir * 73728;
    const float* bias = dir ? biasb : biasf;
    _Float16* cbase = cst + (size_t)dirb * 32 * HW_;
    float* outp = out + ((size_t)(t * 4 + b) * 64 + dir * 32) * HW_;

    const int tid = threadIdx.x;
    const int lane = tid & 63, wq = tid >> 6;   // wq 0..7
    const int px = lane & 15, kg = lane >> 4;

    // Stage FULL W for this dir into LDS.
#pragma unroll
    for (int k = 0; k < 18; ++k) {
        int wb = k * 512 + (tid & ~63);
        gl2lds16(bw + ((size_t)wb + lane) * 8, bsh + (size_t)wb * 8);
    }

    f32x4 acc[4][8];
#pragma unroll
    for (int f = 0; f < 4; ++f)
#pragma unroll
        for (int nf = 0; nf < 8; ++nf) acc[f][nf] = (f32x4)(0.f);

    half8 abuf[4][4];  // [slot][f], rolling depth 4 (pixel frags)

    if (t == 0) {
#pragma unroll
        for (int tp = 0; tp < 4; ++tp) {
            int dy = tp / 3, dx = tp - dy * 3;
#pragma unroll
            for (int f = 0; f < 4; ++f) abuf[tp][f] = lda_nt(base_x, f, dy, dx, px, kg, wq);
        }
        __syncthreads();
#pragma unroll
        for (int tap = 0; tap < 9; ++tap) {
            const int slot = tap & 3;
#pragma unroll
            for (int nf = 0; nf < 8; ++nf) {
                half8 w8 = *(const half8*)(bsh + ((size_t)((tap * 2) * 8 + nf) << 9) + (lane << 3));
#pragma unroll
                for (int f = 0; f < 4; ++f)
                    acc[f][nf] = __builtin_amdgcn_mfma_f32_16x16x32_f16(w8, abuf[slot][f], acc[f][nf], 0, 0, 0);
            }
            if (tap + 4 < 9) {
                const int tn = tap + 4;
                const int dyn_ = tn / 3, dxn = tn - dyn_ * 3;
#pragma unroll
                for (int f = 0; f < 4; ++f) abuf[slot][f] = lda_nt(base_x, f, dyn_, dxn, px, kg, wq);
            }
        }
    } else {
#pragma unroll
        for (int k0 = 0; k0 < 4; ++k0) {
            int tp = k0 >> 1;
            int dy = tp / 3, dx = tp - dy * 3;
#pragma unroll
            for (int f = 0; f < 4; ++f)
                abuf[k0][f] = (k0 & 1) ? lda(base_h, f, dy, dx, px, kg, wq)
                                       : lda_nt(base_x, f, dy, dx, px, kg, wq);
        }
        __syncthreads();
#pragma unroll
        for (int ks = 0; ks < 18; ++ks) {
            const int slot = ks & 3;
#pragma unroll
            for (int nf = 0; nf < 8; ++nf) {
                half8 w8 = *(const half8*)(bsh + ((size_t)(ks * 8 + nf) << 9) + (lane << 3));
#pragma unroll
                for (int f = 0; f < 4; ++f)
                    acc[f][nf] = __builtin_amdgcn_mfma_f32_16x16x32_f16(w8, abuf[slot][f], acc[f][nf], 0, 0, 0);
            }
            if (ks + 4 < 18) {
                const int kn = ks + 4;
                const int tn = kn >> 1;
                const int dyn_ = tn / 3, dxn = tn - dyn_ * 3;
#pragma unroll
                for (int f = 0; f < 4; ++f)
                    abuf[slot][f] = (kn & 1) ? lda(base_h, f, dyn_, dxn, px, kg, wq)
                                             : lda_nt(base_x, f, dyn_, dxn, px, kg, wq);
            }
        }
    }

    // Epilogue (swapped D-layout): col=lane&15 -> PIXEL sub-index; row=kg*4+r -> co sub.
    // Value acc[f][nf][r] at lane: co q = nf*16 + kg*4 + r, pixel = (wq*2+(f>>1), (f&1)*16 + px).
    const int q_kg = kg * 4;
    const int gx0 = (tile & 3) * 32, gy0 = (tile >> 2) * 16;
    const int tx = tile & 3, ty_ = tile >> 2;

    float bI[2][4], bF[2][4], bO[2][4], bG[2][4];
#pragma unroll
    for (int par = 0; par < 2; ++par)
#pragma unroll
        for (int r = 0; r < 4; ++r) {
            int q = par * 16 + q_kg + r;
            bI[par][r] = bias[q];
            bF[par][r] = bias[32 + q];
            bO[par][r] = bias[64 + q];
            bG[par][r] = bias[96 + q];
        }

#pragma unroll
    for (int f = 0; f < 4; ++f) {
        const int prow = wq * 2 + (f >> 1);        // 0..15
        const int col = (f & 1) * 16 + px;         // 0..31, lane-contiguous
        const int gy = gy0 + prow;
        const size_t pixoff = (size_t)gy * W_ + gx0 + col;
        const bool Le = (col == 0) && (tx > 0);
        const bool Re = (col == 31) && (tx < 3);
        const bool Te = (prow == 0) && (ty_ > 0);
        const bool Be = (prow == 15) && (ty_ < 7);
#pragma unroll
        for (int par = 0; par < 2; ++par) {
            f32x4 zi = acc[f][par], zf = acc[f][2 + par], zo = acc[f][4 + par], zg = acc[f][6 + par];
            half4 hv4;
#pragma unroll
            for (int r = 0; r < 4; ++r) {
                const int q = par * 16 + q_kg + r;
                float cold = t ? (float)cbase[(size_t)q * HW_ + pixoff] : 0.f;
                float I = sigf(zi[r] + bI[par][r]);
                float F = sigf(zf[r] + bF[par][r]);
                float O = sigf(zo[r] + bO[par][r]);
                float G = tanhf_(zg[r] + bG[par][r]);
                float cn = F * cold + I * G;
                float hn = O * tanhf_(cn);
                cbase[(size_t)q * HW_ + pixoff] = (_Float16)cn;
                __builtin_nontemporal_store(hn, outp + (size_t)q * HW_ + pixoff);
                hv4[r] = (_Float16)hn;
            }
            // h(t) tile writes: 8B half4 at [pos][ci = par*16+kg*4] (own + halo neighbors).
            const size_t cio = (size_t)(par * 16 + q_kg);
            *(half4*)(&hob[(size_t)tile * TILE_ELEMS + (size_t)((prow + 1) * AW + col + 1) * 32 + cio]) = hv4;
            if (Le) *(half4*)(&hob[(size_t)(tile - 1) * TILE_ELEMS + (size_t)((prow + 1) * AW + 33) * 32 + cio]) = hv4;
            if (Re) *(half4*)(&hob[(size_t)(tile + 1) * TILE_ELEMS + (size_t)((prow + 1) * AW + 0) * 32 + cio]) = hv4;
            if (Te) *(half4*)(&hob[(size_t)(tile - 4) * TILE_ELEMS + (size_t)(17 * AW + col + 1) * 32 + cio]) = hv4;
            if (Be) *(half4*)(&hob[(size_t)(tile + 4) * TILE_ELEMS + (size_t)(0 * AW + col + 1) * 32 + cio]) = hv4;
            if (Te && Le) *(half4*)(&hob[(size_t)(tile - 5) * TILE_ELEMS + (size_t)(17 * AW + 33) * 32 + cio]) = hv4;
            if (Te && Re) *(half4*)(&hob[(size_t)(tile - 3) * TILE_ELEMS + (size_t)(17 * AW + 0) * 32 + cio]) = hv4;
            if (Be && Le) *(half4*)(&hob[(size_t)(tile + 3) * TILE_ELEMS + (size_t)(0 * AW + 33) * 32 + cio]) = hv4;
            if (Be && Re) *(half4*)(&hob[(size_t)(tile + 5) * TILE_ELEMS + (size_t)(0 * AW + 0) * 32 + cio]) = hv4;
        }
    }
}

extern "C" void kernel_launch(void* const* d_in, const int* in_sizes, int n_in,
                              void* d_out, int out_size, void* d_ws, size_t ws_size,
                              hipStream_t stream) {
    const float* x  = (const float*)d_in[0];
    const float* Wf = (const float*)d_in[1];
    const float* bf = (const float*)d_in[2];
    const float* Wb = (const float*)d_in[3];
    const float* bb = (const float*)d_in[4];
    float* out = (float*)d_out;
    char* ws = (char*)d_ws;

    const size_t OFF_WPK = 0;                         // 294,912
    const size_t OFF_XT  = 327680;                    // 80,216,064
    const size_t OFF_H0  = OFF_XT + 80216064;         // 10,027,008
    const size_t OFF_H1  = OFF_H0 + 10027008;         // 10,027,008
    const size_t OFF_C   = OFF_H1 + 10027008;         // 8,388,608 (fp16)

    _Float16* wpk = (_Float16*)(ws + OFF_WPK);
    _Float16* xt  = (_Float16*)(ws + OFF_XT);
    _Float16* hb[2] = { (_Float16*)(ws + OFF_H0), (_Float16*)(ws + OFF_H1) };
    _Float16* cst = (_Float16*)(ws + OFF_C);

    hipFuncSetAttribute((const void*)convlstm_step,
                        hipFuncAttributeMaxDynamicSharedMemorySize, 147456);

    // Zero h ping-pong buffers once (out-of-image halo slots must read as 0).
    hipMemsetAsync(ws + OFF_H0, 0, 2u * 10027008u, stream);

    prep_pack<<<dim3(72), dim3(256), 0, stream>>>(Wf, Wb, wpk);
    prep_xtiles<<<dim3(19584), dim3(256), 0, stream>>>(x, xt);

    for (int t = 0; t < S_; ++t) {
        convlstm_step<<<dim3(8, 32), dim3(512), 147456, stream>>>(
            xt, hb[(t + 1) & 1], hb[t & 1], wpk, bf, bb, cst, out, t);
    }
}

// Round 18
// 622.143 us; speedup vs baseline: 1.0908x; 1.0908x over previous
//
#include <hip/hip_runtime.h>

// BiCLSTM: S=16,B=4,Cin=32,Co=32,H=W=128. fp32 in/out.
// FP16 MFMA implicit-GEMM (r14 base) + c-register-prefetch (r17 with the
// column-group indexing fix: prefetch addr now includes (f&1)*16).
#define S_ 16
#define B_ 4
#define H_ 128
#define W_ 128
#define HW_ (H_ * W_)
#define AH 18
#define AW 34
#define NPOS (AH * AW)          // 612
#define TILE_ELEMS (NPOS * 32)  // 19584 halves per tile A-block

typedef __attribute__((ext_vector_type(8))) _Float16 half8;
typedef __attribute__((ext_vector_type(4))) _Float16 half4;
typedef __attribute__((ext_vector_type(4))) float f32x4;

__device__ __forceinline__ float sigf(float x) { return 1.f / (1.f + __expf(-x)); }
__device__ __forceinline__ float tanhf_(float x) { return 2.f / (1.f + __expf(-2.f * x)) - 1.f; }

__device__ __forceinline__ void gl2lds16(const _Float16* g, _Float16* l) {
    __builtin_amdgcn_global_load_lds(
        (const __attribute__((address_space(1))) unsigned int*)g,
        (__attribute__((address_space(3))) unsigned int*)l, 16, 0, 0);
}

// ---- W-fragment packing: [dir][ks=18][nf=8][lane=64][e=8] fp16 ----
__global__ void prep_pack(const float* __restrict__ Wf, const float* __restrict__ Wb,
                          _Float16* __restrict__ wpk) {
    int id = blockIdx.x * 256 + threadIdx.x;  // 18432
    if (id >= 18432) return;
    int l = id & 63;
    int nf = (id >> 6) & 7;
    int ks = (id >> 9) % 18;
    int d = id / 9216;
    const float* Wsrc = d ? Wb : Wf;
    int tap = ks >> 1, half = ks & 1;
    int dy = tap / 3, dx = tap - dy * 3;
    int co = nf * 16 + (l & 15);
    _Float16* dst = wpk + (size_t)d * 73728 + ((size_t)(ks * 8 + nf) * 64 + l) * 8;
#pragma unroll
    for (int e = 0; e < 8; ++e) {
        int ci = half * 32 + (l >> 4) * 8 + e;
        dst[e] = (_Float16)Wsrc[((co * 64 + ci) * 3 + dy) * 3 + dx];
    }
}

// ---- One-time x -> 16x32-tile layout [ts][b][tile32][pos612][ci32] fp16 ----
__global__ void prep_xtiles(const float* __restrict__ x, _Float16* __restrict__ xt) {
    int id = blockIdx.x * 256 + threadIdx.x;  // 5,013,504
    if (id >= 16 * 4 * 32 * NPOS * 4) return;
    int cb = id & 3;
    int u = id >> 2;            // [ts][b][tile][pos]
    int pos = u % NPOS;
    int v = u / NPOS;
    int tile = v & 31;
    v >>= 5;
    int b = v & 3;
    int ts = v >> 2;
    int ar = pos / AW, ac = pos - ar * AW;
    int gy = (tile >> 2) * 16 + ar - 1;
    int gx = (tile & 3) * 32 + ac - 1;
    bool inb = ((unsigned)gy < 128u) && ((unsigned)gx < 128u);
    const float* g = x + ((size_t)(ts * 4 + b) * 32 + cb * 8) * HW_ + (size_t)gy * W_ + gx;
    half8 vv;
#pragma unroll
    for (int e = 0; e < 8; ++e)
        vv[e] = inb ? (_Float16)__builtin_nontemporal_load(g + e * HW_) : (_Float16)0.f;
    *(half8*)(xt + (size_t)u * 32 + cb * 8) = vv;
}

// A-frag loaders. m-frag f: row = wq*2+(f>>1), colgroup = f&1.
__device__ __forceinline__ half8 lda(const _Float16* __restrict__ base, int f, int dy,
                                     int dx, int px, int kg, int wq) {
    int pos = (wq * 2 + (f >> 1) + dy) * AW + (f & 1) * 16 + px + dx;
    return *(const half8*)(base + (size_t)pos * 32 + kg * 8);
}
__device__ __forceinline__ half8 lda_nt(const _Float16* __restrict__ base, int f, int dy,
                                        int dx, int px, int kg, int wq) {
    int pos = (wq * 2 + (f >> 1) + dy) * AW + (f & 1) * 16 + px + dx;
    return __builtin_nontemporal_load((const half8*)(base + (size_t)pos * 32 + kg * 8));
}

extern __shared__ _Float16 bsh[];  // 147,456 B: [ks*8+nf][lane][e=8], one dir

// One timestep, both directions. grid (8, 32): x = dirb (-> XCD pin), y = tile. 512 thr.
__global__ __launch_bounds__(512, 1)
void convlstm_step(const _Float16* __restrict__ xtiles,
                   const _Float16* __restrict__ hin,
                   _Float16* __restrict__ hout,
                   const _Float16* __restrict__ wpk,
                   const float* __restrict__ biasf, const float* __restrict__ biasb,
                   _Float16* __restrict__ cst,          // fp16 c-state [dirb][32][HW]
                   float* __restrict__ out, int t) {
    const int dirb = blockIdx.x;                        // bid % 8 == dirb -> one XCD
    const int tile = blockIdx.y;
    const int dir = dirb >> 2, b = dirb & 3;
    const int ts = dir ? (S_ - 1 - t) : t;

    const _Float16* base_x = xtiles + ((size_t)(ts * 4 + b) * 32 + tile) * TILE_ELEMS;
    const _Float16* base_h = hin + ((size_t)dirb * 32 + tile) * TILE_ELEMS;
    _Float16* hob = hout + (size_t)dirb * 32 * TILE_ELEMS;
    const _Float16* bw = wpk + (size_t)dir * 73728;
    const float* bias = dir ? biasb : biasf;
    _Float16* cbase = cst + (size_t)dirb * 32 * HW_;
    float* outp = out + ((size_t)(t * 4 + b) * 64 + dir * 32) * HW_;

    const int tid = threadIdx.x;
    const int lane = tid & 63, wq = tid >> 6;   // wq 0..7
    const int px = lane & 15, kg = lane >> 4;

    // Epilogue geometry (needed early for c prefetch).
    const int q0 = px;
    const int gx0 = (tile & 3) * 32, gy0 = (tile >> 2) * 16;
    const int tx = tile & 3, ty_ = tile >> 2;
    const int lx0 = kg * 4;

    // Stage FULL W for this dir into LDS: 9216 chunks of 16B, 18 per thread.
#pragma unroll
    for (int k = 0; k < 18; ++k) {
        int wb = k * 512 + (tid & ~63);          // wave-uniform LDS base
        gl2lds16(bw + ((size_t)wb + lane) * 8, bsh + (size_t)wb * 8);
    }

    f32x4 acc[4][8];
#pragma unroll
    for (int f = 0; f < 4; ++f)
#pragma unroll
        for (int nf = 0; nf < 8; ++nf) acc[f][nf] = (f32x4)(0.f);

    half8 abuf[4][4];  // [slot][f], rolling depth 4
    half4 chp[4][2];   // prefetched c (covered by W-drain + K-loop)

    if (t == 0) {
#pragma unroll
        for (int tp = 0; tp < 4; ++tp) {
            int dy = tp / 3, dx = tp - dy * 3;
#pragma unroll
            for (int f = 0; f < 4; ++f) abuf[tp][f] = lda_nt(base_x, f, dy, dx, px, kg, wq);
        }
        __syncthreads();
#pragma unroll
        for (int tap = 0; tap < 9; ++tap) {
            const int slot = tap & 3;
#pragma unroll
            for (int nf = 0; nf < 8; ++nf) {
                half8 b8 = *(const half8*)(bsh + ((size_t)((tap * 2) * 8 + nf) << 9) + (lane << 3));
#pragma unroll
                for (int f = 0; f < 4; ++f)
                    acc[f][nf] = __builtin_amdgcn_mfma_f32_16x16x32_f16(abuf[slot][f], b8, acc[f][nf], 0, 0, 0);
            }
            if (tap + 4 < 9) {
                const int tn = tap + 4;
                const int dyn_ = tn / 3, dxn = tn - dyn_ * 3;
#pragma unroll
                for (int f = 0; f < 4; ++f) abuf[slot][f] = lda_nt(base_x, f, dyn_, dxn, px, kg, wq);
            }
        }
    } else {
        // Prime A (ks 0..3) and prefetch c, then barrier (waits W staging anyway).
#pragma unroll
        for (int k0 = 0; k0 < 4; ++k0) {
            int tp = k0 >> 1;
            int dy = tp / 3, dx = tp - dy * 3;
#pragma unroll
            for (int f = 0; f < 4; ++f)
                abuf[k0][f] = (k0 & 1) ? lda(base_h, f, dy, dx, px, kg, wq)
                                       : lda_nt(base_x, f, dy, dx, px, kg, wq);
        }
#pragma unroll
        for (int f = 0; f < 4; ++f) {
            const int gy = gy0 + wq * 2 + (f >> 1);
            const int colb = (f & 1) * 16 + lx0;          // FIX: include column group
#pragma unroll
            for (int qs = 0; qs < 2; ++qs) {
                const int q = qs * 16 + q0;
                chp[f][qs] = *(const half4*)(cbase + (size_t)q * HW_ + (size_t)gy * W_ + gx0 + colb);
            }
        }
        __syncthreads();
#pragma unroll
        for (int ks = 0; ks < 18; ++ks) {
            const int slot = ks & 3;
#pragma unroll
            for (int nf = 0; nf < 8; ++nf) {
                half8 b8 = *(const half8*)(bsh + ((size_t)(ks * 8 + nf) << 9) + (lane << 3));
#pragma unroll
                for (int f = 0; f < 4; ++f)
                    acc[f][nf] = __builtin_amdgcn_mfma_f32_16x16x32_f16(abuf[slot][f], b8, acc[f][nf], 0, 0, 0);
            }
            if (ks + 4 < 18) {
                const int kn = ks + 4;
                const int tn = kn >> 1;
                const int dyn_ = tn / 3, dxn = tn - dyn_ * 3;
#pragma unroll
                for (int f = 0; f < 4; ++f)
                    abuf[slot][f] = (kn & 1) ? lda(base_h, f, dyn_, dxn, px, kg, wq)
                                             : lda_nt(base_x, f, dyn_, dxn, px, kg, wq);
            }
        }
    }

    // Epilogue. m-frag f -> row = wq*2+(f>>1), cols (f&1)*16 + kg*4 + r. q0 = px.
    float bI[2], bF[2], bO[2], bG[2];
#pragma unroll
    for (int qs = 0; qs < 2; ++qs) {
        bI[qs] = bias[qs * 16 + q0];
        bF[qs] = bias[32 + qs * 16 + q0];
        bO[qs] = bias[64 + qs * 16 + q0];
        bG[qs] = bias[96 + qs * 16 + q0];
    }
#pragma unroll
    for (int f = 0; f < 4; ++f) {
        const int row = wq * 2 + (f >> 1);
        const int gy = gy0 + row;
        const int colb = (f & 1) * 16 + lx0;
#pragma unroll
        for (int qs = 0; qs < 2; ++qs) {
            const int q = qs * 16 + q0;
            f32x4 zi = acc[f][qs], zf = acc[f][2 + qs], zo = acc[f][4 + qs], zg = acc[f][6 + qs];
            size_t off = (size_t)q * HW_ + (size_t)gy * W_ + gx0 + colb;
            half4 cold4 = (t == 0) ? (half4)((_Float16)0.f) : chp[f][qs];
            half4 cn4;
            f32x4 hn;
#pragma unroll
            for (int r = 0; r < 4; ++r) {
                float I = sigf(zi[r] + bI[qs]);
                float F = sigf(zf[r] + bF[qs]);
                float O = sigf(zo[r] + bO[qs]);
                float G = tanhf_(zg[r] + bG[qs]);
                float cnr = F * (float)cold4[r] + I * G;
                cn4[r] = (_Float16)cnr;
                hn[r] = O * tanhf_(cnr);
            }
            *(half4*)(cbase + off) = cn4;
            __builtin_nontemporal_store(hn, (f32x4*)(outp + off));
#pragma unroll
            for (int r = 0; r < 4; ++r) {
                _Float16 hh = (_Float16)hn[r];
                int col = colb + r;
                hob[(size_t)tile * TILE_ELEMS + (size_t)((row + 1) * AW + col + 1) * 32 + q] = hh;
                bool Le = (col == 0) && (tx > 0);
                bool Re = (col == 31) && (tx < 3);
                bool Te = (row == 0) && (ty_ > 0);
                bool Be = (row == 15) && (ty_ < 7);
                if (Le) hob[(size_t)(tile - 1) * TILE_ELEMS + (size_t)((row + 1) * AW + 33) * 32 + q] = hh;
                if (Re) hob[(size_t)(tile + 1) * TILE_ELEMS + (size_t)((row + 1) * AW + 0) * 32 + q] = hh;
                if (Te) hob[(size_t)(tile - 4) * TILE_ELEMS + (size_t)(17 * AW + col + 1) * 32 + q] = hh;
                if (Be) hob[(size_t)(tile + 4) * TILE_ELEMS + (size_t)(0 * AW + col + 1) * 32 + q] = hh;
                if (Te && Le) hob[(size_t)(tile - 5) * TILE_ELEMS + (size_t)(17 * AW + 33) * 32 + q] = hh;
                if (Te && Re) hob[(size_t)(tile - 3) * TILE_ELEMS + (size_t)(17 * AW + 0) * 32 + q] = hh;
                if (Be && Le) hob[(size_t)(tile + 3) * TILE_ELEMS + (size_t)(0 * AW + 33) * 32 + q] = hh;
                if (Be && Re) hob[(size_t)(tile + 5) * TILE_ELEMS + (size_t)(0 * AW + 0) * 32 + q] = hh;
            }
        }
    }
}

extern "C" void kernel_launch(void* const* d_in, const int* in_sizes, int n_in,
                              void* d_out, int out_size, void* d_ws, size_t ws_size,
                              hipStream_t stream) {
    const float* x  = (const float*)d_in[0];
    const float* Wf = (const float*)d_in[1];
    const float* bf = (const float*)d_in[2];
    const float* Wb = (const float*)d_in[3];
    const float* bb = (const float*)d_in[4];
    float* out = (float*)d_out;
    char* ws = (char*)d_ws;

    const size_t OFF_WPK = 0;                         // 294,912
    const size_t OFF_XT  = 327680;                    // 80,216,064
    const size_t OFF_H0  = OFF_XT + 80216064;         // 10,027,008
    const size_t OFF_H1  = OFF_H0 + 10027008;         // 10,027,008
    const size_t OFF_C   = OFF_H1 + 10027008;         // 8,388,608 (fp16)

    _Float16* wpk = (_Float16*)(ws + OFF_WPK);
    _Float16* xt  = (_Float16*)(ws + OFF_XT);
    _Float16* hb[2] = { (_Float16*)(ws + OFF_H0), (_Float16*)(ws + OFF_H1) };
    _Float16* cst = (_Float16*)(ws + OFF_C);

    hipFuncSetAttribute((const void*)convlstm_step,
                        hipFuncAttributeMaxDynamicSharedMemorySize, 147456);

    // Zero h ping-pong buffers once (out-of-image halo slots must read as 0).
    hipMemsetAsync(ws + OFF_H0, 0, 2u * 10027008u, stream);

    prep_pack<<<dim3(72), dim3(256), 0, stream>>>(Wf, Wb, wpk);
    prep_xtiles<<<dim3(19584), dim3(256), 0, stream>>>(x, xt);

    for (int t = 0; t < S_; ++t) {
        convlstm_step<<<dim3(8, 32), dim3(512), 147456, stream>>>(
            xt, hb[(t + 1) & 1], hb[t & 1], wpk, bf, bb, cst, out, t);
    }
}

// Round 19
// 606.935 us; speedup vs baseline: 1.1181x; 1.0251x over previous
//
#include <hip/hip_runtime.h>

// BiCLSTM: S=16,B=4,Cin=32,Co=32,H=W=128. fp32 in/out.
// FP16 MFMA implicit-GEMM (r14 config = session best, 604us) + prep_xtiles ILP x2.
//  - grid (8,32): blockIdx.x = dirb -> each (dir,b) pinned to one XCD
//  - W fully LDS-resident (144 KiB), barrier-free K-loop, depth-4 A prefetch
//  - x A-loads + out stores nontemporal; c fp16; h scatter into next-step tiles
//  - prep_xtiles: 2 id-slots/thread (16 outstanding loads) for latency cover
#define S_ 16
#define B_ 4
#define H_ 128
#define W_ 128
#define HW_ (H_ * W_)
#define AH 18
#define AW 34
#define NPOS (AH * AW)          // 612
#define TILE_ELEMS (NPOS * 32)  // 19584 halves per tile A-block

typedef __attribute__((ext_vector_type(8))) _Float16 half8;
typedef __attribute__((ext_vector_type(4))) _Float16 half4;
typedef __attribute__((ext_vector_type(4))) float f32x4;

__device__ __forceinline__ float sigf(float x) { return 1.f / (1.f + __expf(-x)); }
__device__ __forceinline__ float tanhf_(float x) { return 2.f / (1.f + __expf(-2.f * x)) - 1.f; }

__device__ __forceinline__ void gl2lds16(const _Float16* g, _Float16* l) {
    __builtin_amdgcn_global_load_lds(
        (const __attribute__((address_space(1))) unsigned int*)g,
        (__attribute__((address_space(3))) unsigned int*)l, 16, 0, 0);
}

// ---- W-fragment packing: [dir][ks=18][nf=8][lane=64][e=8] fp16 ----
__global__ void prep_pack(const float* __restrict__ Wf, const float* __restrict__ Wb,
                          _Float16* __restrict__ wpk) {
    int id = blockIdx.x * 256 + threadIdx.x;  // 18432
    if (id >= 18432) return;
    int l = id & 63;
    int nf = (id >> 6) & 7;
    int ks = (id >> 9) % 18;
    int d = id / 9216;
    const float* Wsrc = d ? Wb : Wf;
    int tap = ks >> 1, half = ks & 1;
    int dy = tap / 3, dx = tap - dy * 3;
    int co = nf * 16 + (l & 15);
    _Float16* dst = wpk + (size_t)d * 73728 + ((size_t)(ks * 8 + nf) * 64 + l) * 8;
#pragma unroll
    for (int e = 0; e < 8; ++e) {
        int ci = half * 32 + (l >> 4) * 8 + e;
        dst[e] = (_Float16)Wsrc[((co * 64 + ci) * 3 + dy) * 3 + dx];
    }
}

// ---- One-time x -> 16x32-tile layout [ts][b][tile32][pos612][ci32] fp16 ----
// v3: 2 id-slots per thread for doubled memory-level parallelism.
#define XT_TOTAL (16 * 4 * 32 * NPOS * 4)   // 5,013,504
#define XT_HALF  (XT_TOTAL / 2)             // 2,506,752
__global__ void prep_xtiles(const float* __restrict__ x, _Float16* __restrict__ xt) {
    int id0 = blockIdx.x * 256 + threadIdx.x;
    if (id0 >= XT_HALF) return;
#pragma unroll
    for (int rep = 0; rep < 2; ++rep) {
        int id = id0 + rep * XT_HALF;
        int cb = id & 3;
        int u = id >> 2;            // [ts][b][tile][pos]
        int pos = u % NPOS;
        int v = u / NPOS;
        int tile = v & 31;
        v >>= 5;
        int b = v & 3;
        int ts = v >> 2;
        int ar = pos / AW, ac = pos - ar * AW;
        int gy = (tile >> 2) * 16 + ar - 1;
        int gx = (tile & 3) * 32 + ac - 1;
        bool inb = ((unsigned)gy < 128u) && ((unsigned)gx < 128u);
        const float* g = x + ((size_t)(ts * 4 + b) * 32 + cb * 8) * HW_ + (size_t)gy * W_ + gx;
        half8 vv;
#pragma unroll
        for (int e = 0; e < 8; ++e)
            vv[e] = inb ? (_Float16)__builtin_nontemporal_load(g + e * HW_) : (_Float16)0.f;
        *(half8*)(xt + (size_t)u * 32 + cb * 8) = vv;
    }
}

// A-frag loaders. m-frag f: row = wq*2+(f>>1), colgroup = f&1.
__device__ __forceinline__ half8 lda(const _Float16* __restrict__ base, int f, int dy,
                                     int dx, int px, int kg, int wq) {
    int pos = (wq * 2 + (f >> 1) + dy) * AW + (f & 1) * 16 + px + dx;
    return *(const half8*)(base + (size_t)pos * 32 + kg * 8);
}
__device__ __forceinline__ half8 lda_nt(const _Float16* __restrict__ base, int f, int dy,
                                        int dx, int px, int kg, int wq) {
    int pos = (wq * 2 + (f >> 1) + dy) * AW + (f & 1) * 16 + px + dx;
    return __builtin_nontemporal_load((const half8*)(base + (size_t)pos * 32 + kg * 8));
}

extern __shared__ _Float16 bsh[];  // 147,456 B: [ks*8+nf][lane][e=8], one dir

// One timestep, both directions. grid (8, 32): x = dirb (-> XCD pin), y = tile. 512 thr.
__global__ __launch_bounds__(512, 1)
void convlstm_step(const _Float16* __restrict__ xtiles,
                   const _Float16* __restrict__ hin,
                   _Float16* __restrict__ hout,
                   const _Float16* __restrict__ wpk,
                   const float* __restrict__ biasf, const float* __restrict__ biasb,
                   _Float16* __restrict__ cst,          // fp16 c-state [dirb][32][HW]
                   float* __restrict__ out, int t) {
    const int dirb = blockIdx.x;                        // bid % 8 == dirb -> one XCD
    const int tile = blockIdx.y;
    const int dir = dirb >> 2, b = dirb & 3;
    const int ts = dir ? (S_ - 1 - t) : t;

    const _Float16* base_x = xtiles + ((size_t)(ts * 4 + b) * 32 + tile) * TILE_ELEMS;
    const _Float16* base_h = hin + ((size_t)dirb * 32 + tile) * TILE_ELEMS;
    _Float16* hob = hout + (size_t)dirb * 32 * TILE_ELEMS;
    const _Float16* bw = wpk + (size_t)dir * 73728;
    const float* bias = dir ? biasb : biasf;
    _Float16* cbase = cst + (size_t)dirb * 32 * HW_;
    float* outp = out + ((size_t)(t * 4 + b) * 64 + dir * 32) * HW_;

    const int tid = threadIdx.x;
    const int lane = tid & 63, wq = tid >> 6;   // wq 0..7
    const int px = lane & 15, kg = lane >> 4;

    // Stage FULL W for this dir into LDS: 9216 chunks of 16B, 18 per thread.
#pragma unroll
    for (int k = 0; k < 18; ++k) {
        int wb = k * 512 + (tid & ~63);          // wave-uniform LDS base
        gl2lds16(bw + ((size_t)wb + lane) * 8, bsh + (size_t)wb * 8);
    }

    f32x4 acc[4][8];
#pragma unroll
    for (int f = 0; f < 4; ++f)
#pragma unroll
        for (int nf = 0; nf < 8; ++nf) acc[f][nf] = (f32x4)(0.f);

    half8 abuf[4][4];  // [slot][f], rolling depth 4

    if (t == 0) {
#pragma unroll
        for (int tp = 0; tp < 4; ++tp) {
            int dy = tp / 3, dx = tp - dy * 3;
#pragma unroll
            for (int f = 0; f < 4; ++f) abuf[tp][f] = lda_nt(base_x, f, dy, dx, px, kg, wq);
        }
        __syncthreads();
#pragma unroll
        for (int tap = 0; tap < 9; ++tap) {
            const int slot = tap & 3;
#pragma unroll
            for (int nf = 0; nf < 8; ++nf) {
                half8 b8 = *(const half8*)(bsh + ((size_t)((tap * 2) * 8 + nf) << 9) + (lane << 3));
#pragma unroll
                for (int f = 0; f < 4; ++f)
                    acc[f][nf] = __builtin_amdgcn_mfma_f32_16x16x32_f16(abuf[slot][f], b8, acc[f][nf], 0, 0, 0);
            }
            if (tap + 4 < 9) {
                const int tn = tap + 4;
                const int dyn_ = tn / 3, dxn = tn - dyn_ * 3;
#pragma unroll
                for (int f = 0; f < 4; ++f) abuf[slot][f] = lda_nt(base_x, f, dyn_, dxn, px, kg, wq);
            }
        }
    } else {
        // 18 ks: even = x (nt), odd = h (L2-local). Depth-4 prefetch, no barriers.
#pragma unroll
        for (int k0 = 0; k0 < 4; ++k0) {
            int tp = k0 >> 1;
            int dy = tp / 3, dx = tp - dy * 3;
#pragma unroll
            for (int f = 0; f < 4; ++f)
                abuf[k0][f] = (k0 & 1) ? lda(base_h, f, dy, dx, px, kg, wq)
                                       : lda_nt(base_x, f, dy, dx, px, kg, wq);
        }
        __syncthreads();
#pragma unroll
        for (int ks = 0; ks < 18; ++ks) {
            const int slot = ks & 3;
#pragma unroll
            for (int nf = 0; nf < 8; ++nf) {
                half8 b8 = *(const half8*)(bsh + ((size_t)(ks * 8 + nf) << 9) + (lane << 3));
#pragma unroll
                for (int f = 0; f < 4; ++f)
                    acc[f][nf] = __builtin_amdgcn_mfma_f32_16x16x32_f16(abuf[slot][f], b8, acc[f][nf], 0, 0, 0);
            }
            if (ks + 4 < 18) {
                const int kn = ks + 4;
                const int tn = kn >> 1;
                const int dyn_ = tn / 3, dxn = tn - dyn_ * 3;
#pragma unroll
                for (int f = 0; f < 4; ++f)
                    abuf[slot][f] = (kn & 1) ? lda(base_h, f, dyn_, dxn, px, kg, wq)
                                             : lda_nt(base_x, f, dyn_, dxn, px, kg, wq);
            }
        }
    }

    // Epilogue. m-frag f -> row = wq*2+(f>>1), cols (f&1)*16 + kg*4 + r. q0 = px.
    const int q0 = px;
    const int gx0 = (tile & 3) * 32, gy0 = (tile >> 2) * 16;
    const int tx = tile & 3, ty_ = tile >> 2;
    const int lx0 = kg * 4;

    float bI[2], bF[2], bO[2], bG[2];
#pragma unroll
    for (int qs = 0; qs < 2; ++qs) {
        bI[qs] = bias[qs * 16 + q0];
        bF[qs] = bias[32 + qs * 16 + q0];
        bO[qs] = bias[64 + qs * 16 + q0];
        bG[qs] = bias[96 + qs * 16 + q0];
    }
#pragma unroll
    for (int f = 0; f < 4; ++f) {
        const int row = wq * 2 + (f >> 1);
        const int gy = gy0 + row;
        const int colb = (f & 1) * 16 + lx0;
#pragma unroll
        for (int qs = 0; qs < 2; ++qs) {
            const int q = qs * 16 + q0;
            f32x4 zi = acc[f][qs], zf = acc[f][2 + qs], zo = acc[f][4 + qs], zg = acc[f][6 + qs];
            size_t off = (size_t)q * HW_ + (size_t)gy * W_ + gx0 + colb;
            half4 cold4 = (half4)((_Float16)0.f);
            if (t) cold4 = *(const half4*)(cbase + off);
            half4 cn4;
            f32x4 hn;
#pragma unroll
            for (int r = 0; r < 4; ++r) {
                float I = sigf(zi[r] + bI[qs]);
                float F = sigf(zf[r] + bF[qs]);
                float O = sigf(zo[r] + bO[qs]);
                float G = tanhf_(zg[r] + bG[qs]);
                float cnr = F * (float)cold4[r] + I * G;
                cn4[r] = (_Float16)cnr;
                hn[r] = O * tanhf_(cnr);
            }
            *(half4*)(cbase + off) = cn4;
            __builtin_nontemporal_store(hn, (f32x4*)(outp + off));
#pragma unroll
            for (int r = 0; r < 4; ++r) {
                _Float16 hh = (_Float16)hn[r];
                int col = colb + r;
                hob[(size_t)tile * TILE_ELEMS + (size_t)((row + 1) * AW + col + 1) * 32 + q] = hh;
                bool Le = (col == 0) && (tx > 0);
                bool Re = (col == 31) && (tx < 3);
                bool Te = (row == 0) && (ty_ > 0);
                bool Be = (row == 15) && (ty_ < 7);
                if (Le) hob[(size_t)(tile - 1) * TILE_ELEMS + (size_t)((row + 1) * AW + 33) * 32 + q] = hh;
                if (Re) hob[(size_t)(tile + 1) * TILE_ELEMS + (size_t)((row + 1) * AW + 0) * 32 + q] = hh;
                if (Te) hob[(size_t)(tile - 4) * TILE_ELEMS + (size_t)(17 * AW + col + 1) * 32 + q] = hh;
                if (Be) hob[(size_t)(tile + 4) * TILE_ELEMS + (size_t)(0 * AW + col + 1) * 32 + q] = hh;
                if (Te && Le) hob[(size_t)(tile - 5) * TILE_ELEMS + (size_t)(17 * AW + 33) * 32 + q] = hh;
                if (Te && Re) hob[(size_t)(tile - 3) * TILE_ELEMS + (size_t)(17 * AW + 0) * 32 + q] = hh;
                if (Be && Le) hob[(size_t)(tile + 3) * TILE_ELEMS + (size_t)(0 * AW + 33) * 32 + q] = hh;
                if (Be && Re) hob[(size_t)(tile + 5) * TILE_ELEMS + (size_t)(0 * AW + 0) * 32 + q] = hh;
            }
        }
    }
}

extern "C" void kernel_launch(void* const* d_in, const int* in_sizes, int n_in,
                              void* d_out, int out_size, void* d_ws, size_t ws_size,
                              hipStream_t stream) {
    const float* x  = (const float*)d_in[0];
    const float* Wf = (const float*)d_in[1];
    const float* bf = (const float*)d_in[2];
    const float* Wb = (const float*)d_in[3];
    const float* bb = (const float*)d_in[4];
    float* out = (float*)d_out;
    char* ws = (char*)d_ws;

    const size_t OFF_WPK = 0;                         // 294,912
    const size_t OFF_XT  = 327680;                    // 80,216,064
    const size_t OFF_H0  = OFF_XT + 80216064;         // 10,027,008
    const size_t OFF_H1  = OFF_H0 + 10027008;         // 10,027,008
    const size_t OFF_C   = OFF_H1 + 10027008;         // 8,388,608 (fp16)

    _Float16* wpk = (_Float16*)(ws + OFF_WPK);
    _Float16* xt  = (_Float16*)(ws + OFF_XT);
    _Float16* hb[2] = { (_Float16*)(ws + OFF_H0), (_Float16*)(ws + OFF_H1) };
    _Float16* cst = (_Float16*)(ws + OFF_C);

    hipFuncSetAttribute((const void*)convlstm_step,
                        hipFuncAttributeMaxDynamicSharedMemorySize, 147456);

    // Zero h ping-pong buffers once (out-of-image halo slots must read as 0).
    hipMemsetAsync(ws + OFF_H0, 0, 2u * 10027008u, stream);

    prep_pack<<<dim3(72), dim3(256), 0, stream>>>(Wf, Wb, wpk);
    prep_xtiles<<<dim3(9792), dim3(256), 0, stream>>>(x, xt);

    for (int t = 0; t < S_; ++t) {
        convlstm_step<<<dim3(8, 32), dim3(512), 147456, stream>>>(
            xt, hb[(t + 1) & 1], hb[t & 1], wpk, bf, bb, cst, out, t);
    }
}